// Round 1
// baseline (228.411 us; speedup 1.0000x reference)
//
#include <hip/hip_runtime.h>
#include <hip/hip_bf16.h>

// Problem constants (N=4096 rows, D=2048 cols, T=0.5 -> 1/T = 2)
#define NR 4096
#define DD 2048
#define INV_T 2.0f

typedef __attribute__((ext_vector_type(8))) short short8;
typedef __attribute__((ext_vector_type(8))) unsigned short ushort8;
typedef __attribute__((ext_vector_type(4))) float floatx4;

static __device__ __forceinline__ void async_copy16(const void* g, void* lds) {
  __builtin_amdgcn_global_load_lds((const __attribute__((address_space(1))) void*)g,
                                   (__attribute__((address_space(3))) void*)lds,
                                   16, 0, 0);
}

static __device__ __forceinline__ unsigned short f2bf(float x) {
  __hip_bfloat16 h = __float2bfloat16(x);
  return *reinterpret_cast<unsigned short*>(&h);
}

// ---------------------------------------------------------------------------
// Kernel 1: per-row L2 normalize.
//  mat 0 (x_source):    write bf16 normalized rows to a16, store inv_norm
//  mat 1 (x_bc_target): store inv_norm only (only column-sums needed)
//  mat 2 (x_raw_target): write bf16 normalized rows to c16
// grid (NR, 3), block 256
// ---------------------------------------------------------------------------
__global__ __launch_bounds__(256) void normalize_kernel(
    const float* __restrict__ src, const float* __restrict__ bc,
    const float* __restrict__ raw,
    unsigned short* __restrict__ a16, unsigned short* __restrict__ c16,
    float* __restrict__ inv_a, float* __restrict__ inv_b) {
  const int row = blockIdx.x;
  const int mat = blockIdx.y;
  const int tid = threadIdx.x;
  const float* base = (mat == 0) ? src : ((mat == 1) ? bc : raw);
  const float4* b4 = (const float4*)(base + (size_t)row * DD);

  float4 v0 = b4[tid * 2];
  float4 v1 = b4[tid * 2 + 1];
  float ss = v0.x * v0.x + v0.y * v0.y + v0.z * v0.z + v0.w * v0.w +
             v1.x * v1.x + v1.y * v1.y + v1.z * v1.z + v1.w * v1.w;
  #pragma unroll
  for (int off = 32; off > 0; off >>= 1) ss += __shfl_down(ss, off, 64);

  __shared__ float sred[4];
  __shared__ float sinv;
  if ((tid & 63) == 0) sred[tid >> 6] = ss;
  __syncthreads();
  if (tid == 0) sinv = rsqrtf(sred[0] + sred[1] + sred[2] + sred[3]);
  __syncthreads();
  const float inv = sinv;

  if (mat == 1) {
    if (tid == 0) inv_b[row] = inv;
    return;
  }
  ushort8 o;
  o[0] = f2bf(v0.x * inv); o[1] = f2bf(v0.y * inv);
  o[2] = f2bf(v0.z * inv); o[3] = f2bf(v0.w * inv);
  o[4] = f2bf(v1.x * inv); o[5] = f2bf(v1.y * inv);
  o[6] = f2bf(v1.z * inv); o[7] = f2bf(v1.w * inv);
  unsigned short* dst = ((mat == 0) ? a16 : c16) + (size_t)row * DD + tid * 8;
  *(ushort8*)dst = o;
  if (mat == 0 && tid == 0) inv_a[row] = inv;
}

// ---------------------------------------------------------------------------
// Kernel 2: column sums of normalized source / bc_target.
//  s_a[d] = sum_i src[i,d]*inv_a[i], s_b[d] = sum_i bc[i,d]*inv_b[i]
// grid (DD/256, 32), block 256; partial over 128 rows each, atomicAdd.
// ---------------------------------------------------------------------------
__global__ __launch_bounds__(256) void colsum_kernel(
    const float* __restrict__ src, const float* __restrict__ bc,
    const float* __restrict__ inv_a, const float* __restrict__ inv_b,
    float* __restrict__ s_a, float* __restrict__ s_b) {
  const int d = blockIdx.x * 256 + threadIdx.x;
  const int r0 = blockIdx.y * 128;
  float sa = 0.f, sb = 0.f;
  #pragma unroll 4
  for (int i = 0; i < 128; i++) {
    const int r = r0 + i;
    sa += src[(size_t)r * DD + d] * inv_a[r];
    sb += bc[(size_t)r * DD + d] * inv_b[r];
  }
  atomicAdd(&s_a[d], sa);
  atomicAdd(&s_b[d], sb);
}

// ---------------------------------------------------------------------------
// Kernel 3: bf16 MFMA GEMM a_n @ c_n^T with fused sum(exp(sim/T)) epilogue.
// 128x128 tile, BK=32, 16x16x32 MFMA, global_load_lds width-16 staging
// (m97 structure). Score matrix never materialized; per-block partial exp
// sums atomicAdd'ed into S_exp. Full-reduction epilogue is insensitive to
// the C/D lane->(row,col) mapping.
// grid (32, 32), block 256 (4 waves; each wave owns a 64x64 quadrant).
// ---------------------------------------------------------------------------
__global__ __launch_bounds__(256, 2) void gemm_expsum_kernel(
    const unsigned short* __restrict__ a16, const unsigned short* __restrict__ c16,
    float* __restrict__ S_exp) {
  __shared__ short As[128 * 32];  // [row][k] bf16, 64B rows
  __shared__ short Cs[128 * 32];
  const int tid = threadIdx.x;
  const int lane = tid & 63;
  const int wave = tid >> 6;
  const int wr = wave >> 1;       // wave row quadrant (0/1)
  const int wc = wave & 1;        // wave col quadrant (0/1)
  const int quad = lane >> 4;     // k-block selector for fragments
  const int l16 = lane & 15;
  const int br = blockIdx.x, bc = blockIdx.y;

  floatx4 acc[4][4] = {};

  // staging: each wave moves 2 x 1KB chunks of each tile.
  // chunk c = 16 rows x 64B; lane L -> row c*16 + L/4, byte off (L&3)*16.
  const int sr0 = (wave * 2 + 0) * 16 + (lane >> 2);
  const int sr1 = (wave * 2 + 1) * 16 + (lane >> 2);
  const int sk = (lane & 3) * 8;  // elements
  const short* gA0 = (const short*)a16 + (size_t)(br * 128 + sr0) * DD + sk;
  const short* gA1 = (const short*)a16 + (size_t)(br * 128 + sr1) * DD + sk;
  const short* gC0 = (const short*)c16 + (size_t)(bc * 128 + sr0) * DD + sk;
  const short* gC1 = (const short*)c16 + (size_t)(bc * 128 + sr1) * DD + sk;
  short* lA0 = &As[(wave * 2 + 0) * 512];  // 512 shorts = 1KB; +lane*16B by HW
  short* lA1 = &As[(wave * 2 + 1) * 512];
  short* lC0 = &Cs[(wave * 2 + 0) * 512];
  short* lC1 = &Cs[(wave * 2 + 1) * 512];

  for (int kt = 0; kt < DD / 32; kt++) {
    async_copy16(gA0, lA0);
    async_copy16(gA1, lA1);
    async_copy16(gC0, lC0);
    async_copy16(gC1, lC1);
    gA0 += 32; gA1 += 32; gC0 += 32; gC1 += 32;
    __syncthreads();  // drains vmcnt (global_load_lds) + barrier

    short8 af[4], bf[4];
    #pragma unroll
    for (int i = 0; i < 4; i++)
      af[i] = *(const short8*)&As[(wr * 64 + i * 16 + l16) * 32 + quad * 8];
    #pragma unroll
    for (int j = 0; j < 4; j++)
      bf[j] = *(const short8*)&Cs[(wc * 64 + j * 16 + l16) * 32 + quad * 8];
    #pragma unroll
    for (int i = 0; i < 4; i++)
      #pragma unroll
      for (int j = 0; j < 4; j++)
        acc[i][j] = __builtin_amdgcn_mfma_f32_16x16x32_bf16(af[i], bf[j], acc[i][j], 0, 0, 0);
    __syncthreads();  // all waves done reading LDS before restage
  }

  // epilogue: sum exp(sim * (1/T)) over this block's 128x128 tile
  float local = 0.f;
  #pragma unroll
  for (int i = 0; i < 4; i++)
    #pragma unroll
    for (int j = 0; j < 4; j++)
      #pragma unroll
      for (int r = 0; r < 4; r++)
        local += __expf(acc[i][j][r] * INV_T);
  #pragma unroll
  for (int off = 32; off > 0; off >>= 1) local += __shfl_down(local, off, 64);
  __shared__ float red[4];
  if (lane == 0) red[wave] = local;
  __syncthreads();
  if (tid == 0) atomicAdd(S_exp, red[0] + red[1] + red[2] + red[3]);
}

// ---------------------------------------------------------------------------
// Kernel 4: finalize. loss = log(S_exp) - (dot(s_a,s_b)/N^2)*(1/T)
// ---------------------------------------------------------------------------
__global__ __launch_bounds__(256) void finalize_kernel(
    const float* __restrict__ s_a, const float* __restrict__ s_b,
    const float* __restrict__ S_exp, float* __restrict__ out) {
  const int tid = threadIdx.x;
  float p = 0.f;
  for (int d = tid; d < DD; d += 256) p += s_a[d] * s_b[d];
  #pragma unroll
  for (int off = 32; off > 0; off >>= 1) p += __shfl_down(p, off, 64);
  __shared__ float red[4];
  if ((tid & 63) == 0) red[tid >> 6] = p;
  __syncthreads();
  if (tid == 0) {
    const float dot = red[0] + red[1] + red[2] + red[3];
    out[0] = logf(S_exp[0]) - dot * (INV_T / ((float)NR * (float)NR));
  }
}

extern "C" void kernel_launch(void* const* d_in, const int* in_sizes, int n_in,
                              void* d_out, int out_size, void* d_ws, size_t ws_size,
                              hipStream_t stream) {
  const float* src = (const float*)d_in[0];
  const float* bc  = (const float*)d_in[1];
  const float* raw = (const float*)d_in[2];

  char* ws = (char*)d_ws;
  unsigned short* a16 = (unsigned short*)ws;                              // 16 MiB
  unsigned short* c16 = (unsigned short*)(ws + (size_t)16 * 1024 * 1024); // 16 MiB
  float* inv_a = (float*)(ws + (size_t)32 * 1024 * 1024);                 // 16 KiB
  float* inv_b = inv_a + NR;                                              // 16 KiB
  float* s_a   = inv_b + NR;                                              // 8 KiB
  float* s_b   = s_a + DD;                                                // 8 KiB
  float* S_exp = s_b + DD;                                                // 4 B

  // zero accumulators (ws is poisoned 0xAA before every launch)
  hipMemsetAsync(s_a, 0, (2 * DD + 1) * sizeof(float), stream);

  normalize_kernel<<<dim3(NR, 3), 256, 0, stream>>>(src, bc, raw, a16, c16, inv_a, inv_b);
  colsum_kernel<<<dim3(DD / 256, 32), 256, 0, stream>>>(src, bc, inv_a, inv_b, s_a, s_b);
  gemm_expsum_kernel<<<dim3(32, 32), 256, 0, stream>>>(a16, c16, S_exp);
  finalize_kernel<<<1, 256, 0, stream>>>(s_a, s_b, S_exp, (float*)d_out);
}

// Round 2
// 186.563 us; speedup vs baseline: 1.2243x; 1.2243x over previous
//
#include <hip/hip_runtime.h>
#include <hip/hip_bf16.h>

// Problem constants (N=4096 rows, D=2048 cols, T=0.5 -> 1/T = 2)
#define NR 4096
#define DD 2048
#define INV_T 2.0f
// fp8 quantization pre-scale: a_n*32 stays in e4m3 normal range (max 32 < 448)
#define QSCALE 32.0f
// MFMA output = (32*sim_a)·(32*sim_b) accumulated = 1024*sim
#define ACC_TO_LOGIT (INV_T / (QSCALE * QSCALE))  // 2/1024

typedef __attribute__((ext_vector_type(4))) float floatx4;
typedef __attribute__((ext_vector_type(4))) int int4v;
typedef __attribute__((ext_vector_type(8))) int int8v;

static __device__ __forceinline__ void async_copy16(const void* g, void* lds) {
  __builtin_amdgcn_global_load_lds((const __attribute__((address_space(1))) void*)g,
                                   (__attribute__((address_space(3))) void*)lds,
                                   16, 0, 0);
}

// ---------------------------------------------------------------------------
// Kernel 1: per-row L2 normalize.
//  mat 0 (x_source):    write fp8 e4m3 of (row*inv_norm*32) to a8, store inv
//  mat 1 (x_bc_target): store inv_norm only (only column-sums needed)
//  mat 2 (x_raw_target): write fp8 to c8
// grid (NR, 3), block 256
// ---------------------------------------------------------------------------
__global__ __launch_bounds__(256) void normalize_kernel(
    const float* __restrict__ src, const float* __restrict__ bc,
    const float* __restrict__ raw,
    unsigned char* __restrict__ a8, unsigned char* __restrict__ c8,
    float* __restrict__ inv_a, float* __restrict__ inv_b) {
  const int row = blockIdx.x;
  const int mat = blockIdx.y;
  const int tid = threadIdx.x;
  const float* base = (mat == 0) ? src : ((mat == 1) ? bc : raw);
  const float4* b4 = (const float4*)(base + (size_t)row * DD);

  float4 v0 = b4[tid * 2];
  float4 v1 = b4[tid * 2 + 1];
  float ss = v0.x * v0.x + v0.y * v0.y + v0.z * v0.z + v0.w * v0.w +
             v1.x * v1.x + v1.y * v1.y + v1.z * v1.z + v1.w * v1.w;
  #pragma unroll
  for (int off = 32; off > 0; off >>= 1) ss += __shfl_down(ss, off, 64);

  __shared__ float sred[4];
  __shared__ float sinv;
  if ((tid & 63) == 0) sred[tid >> 6] = ss;
  __syncthreads();
  if (tid == 0) sinv = rsqrtf(sred[0] + sred[1] + sred[2] + sred[3]);
  __syncthreads();
  const float inv = sinv;

  if (mat == 1) {
    if (tid == 0) inv_b[row] = inv;
    return;
  }
  // pack 8 floats -> 8 fp8 e4m3 bytes (HW cvt, RNE, OCP format on gfx950)
  const float s = inv * QSCALE;
  int d0 = __builtin_amdgcn_cvt_pk_fp8_f32(v0.x * s, v0.y * s, 0, false);
  d0 = __builtin_amdgcn_cvt_pk_fp8_f32(v0.z * s, v0.w * s, d0, true);
  int d1 = __builtin_amdgcn_cvt_pk_fp8_f32(v1.x * s, v1.y * s, 0, false);
  d1 = __builtin_amdgcn_cvt_pk_fp8_f32(v1.z * s, v1.w * s, d1, true);
  int2 o; o.x = d0; o.y = d1;
  unsigned char* dst = ((mat == 0) ? a8 : c8) + (size_t)row * DD + tid * 8;
  *(int2*)dst = o;
  if (mat == 0 && tid == 0) inv_a[row] = inv;
}

// ---------------------------------------------------------------------------
// Kernel 2: column sums of normalized source / bc_target (fp32, exact).
//  s_a[d] = sum_i src[i,d]*inv_a[i], s_b[d] = sum_i bc[i,d]*inv_b[i]
// grid (DD/256, 32), block 256; partial over 128 rows each, atomicAdd.
// ---------------------------------------------------------------------------
__global__ __launch_bounds__(256) void colsum_kernel(
    const float* __restrict__ src, const float* __restrict__ bc,
    const float* __restrict__ inv_a, const float* __restrict__ inv_b,
    float* __restrict__ s_a, float* __restrict__ s_b) {
  const int d = blockIdx.x * 256 + threadIdx.x;
  const int r0 = blockIdx.y * 128;
  float sa = 0.f, sb = 0.f;
  #pragma unroll 4
  for (int i = 0; i < 128; i++) {
    const int r = r0 + i;
    sa += src[(size_t)r * DD + d] * inv_a[r];
    sb += bc[(size_t)r * DD + d] * inv_b[r];
  }
  atomicAdd(&s_a[d], sa);
  atomicAdd(&s_b[d], sb);
}

// ---------------------------------------------------------------------------
// Kernel 3: MX-fp8 MFMA GEMM a_n @ c_n^T with fused sum(exp(sim/T)) epilogue.
// 128x128 tile, BK=128 bytes, 16x16x128 f8f6f4 MFMA (identity E8M0 scales),
// global_load_lds width-16 staging with XOR swizzle applied on the SOURCE
// address (LDS dest is wave-uniform base + lane*16, so swizzle must be on
// the gather side): global chunk (row,c) lands at LDS chunk (row, c^(row&7)).
// Fragment ds_read_b128s then hit 8 distinct chunk columns -> 2-way bank
// aliasing only (free, m136), vs 8-way in the bf16 round-1 kernel (8.4M
// conflict cycles).
// grid (32, 32), block 256 (4 waves; each wave owns a 64x64 quadrant).
// ---------------------------------------------------------------------------
__global__ __launch_bounds__(256, 2) void gemm_expsum_kernel(
    const unsigned char* __restrict__ a8, const unsigned char* __restrict__ c8,
    float* __restrict__ S_exp) {
  __shared__ unsigned char As[128 * 128];  // [row][chunk^(row&7)] 16KB
  __shared__ unsigned char Cs[128 * 128];
  const int tid = threadIdx.x;
  const int lane = tid & 63;
  const int wave = tid >> 6;
  const int wr = wave >> 1;       // wave row quadrant (0/1)
  const int wc = wave & 1;        // wave col quadrant (0/1)
  const int quad = lane >> 4;     // k-chunk-pair selector for fragments
  const int l16 = lane & 15;
  const int br = blockIdx.x, bc = blockIdx.y;

  floatx4 acc[4][4] = {};

  // staging: per matrix, 16 windows of 1KB (8 rows x 128B); 4 per wave.
  // lane l -> window row l>>3, LDS chunk l&7; source chunk swizzled.
  const int wrow = lane >> 3;
  const int csrc = (lane & 7) ^ (wrow & 7);
  const unsigned char* gA[4];
  const unsigned char* gC[4];
  unsigned char* lA[4];
  unsigned char* lC[4];
  #pragma unroll
  for (int q = 0; q < 4; q++) {
    const int m = wave * 4 + q;
    const int row = m * 8 + wrow;
    gA[q] = a8 + (size_t)(br * 128 + row) * DD + csrc * 16;
    gC[q] = c8 + (size_t)(bc * 128 + row) * DD + csrc * 16;
    lA[q] = &As[m * 1024];
    lC[q] = &Cs[m * 1024];
  }

  for (int kt = 0; kt < DD / 128; kt++) {
    #pragma unroll
    for (int q = 0; q < 4; q++) {
      async_copy16(gA[q], lA[q]);
      async_copy16(gC[q], lC[q]);
      gA[q] += 128; gC[q] += 128;
    }
    __syncthreads();  // drains vmcnt (global_load_lds) + barrier

    // fragments: lane holds A[row=l16][k = quad*32 .. quad*32+32) as 8 dwords
    int8v af[4], bf[4];
    #pragma unroll
    for (int i = 0; i < 4; i++) {
      const int r = wr * 64 + i * 16 + l16;
      const int c0 = (2 * quad) ^ (r & 7);
      const int c1 = (2 * quad + 1) ^ (r & 7);
      int4v lo = *(const int4v*)&As[r * 128 + c0 * 16];
      int4v hi = *(const int4v*)&As[r * 128 + c1 * 16];
      af[i] = int8v{lo[0], lo[1], lo[2], lo[3], hi[0], hi[1], hi[2], hi[3]};
    }
    #pragma unroll
    for (int j = 0; j < 4; j++) {
      const int r = wc * 64 + j * 16 + l16;
      const int c0 = (2 * quad) ^ (r & 7);
      const int c1 = (2 * quad + 1) ^ (r & 7);
      int4v lo = *(const int4v*)&Cs[r * 128 + c0 * 16];
      int4v hi = *(const int4v*)&Cs[r * 128 + c1 * 16];
      bf[j] = int8v{lo[0], lo[1], lo[2], lo[3], hi[0], hi[1], hi[2], hi[3]};
    }
    #pragma unroll
    for (int i = 0; i < 4; i++)
      #pragma unroll
      for (int j = 0; j < 4; j++)
        acc[i][j] = __builtin_amdgcn_mfma_scale_f32_16x16x128_f8f6f4(
            af[i], bf[j], acc[i][j], 0 /*cbsz: fp8*/, 0 /*blgp: fp8*/,
            0, 0x7F7F7F7F, 0, 0x7F7F7F7F /*E8M0 identity scales*/);
    __syncthreads();  // all waves done reading LDS before restage
  }

  // epilogue: sum exp(sim/T) over this block's 128x128 tile; acc = 1024*sim.
  float local = 0.f;
  #pragma unroll
  for (int i = 0; i < 4; i++)
    #pragma unroll
    for (int j = 0; j < 4; j++)
      #pragma unroll
      for (int r = 0; r < 4; r++)
        local += __expf(acc[i][j][r] * ACC_TO_LOGIT);
  #pragma unroll
  for (int off = 32; off > 0; off >>= 1) local += __shfl_down(local, off, 64);
  __shared__ float red[4];
  if (lane == 0) red[wave] = local;
  __syncthreads();
  if (tid == 0) atomicAdd(S_exp, red[0] + red[1] + red[2] + red[3]);
}

// ---------------------------------------------------------------------------
// Kernel 4: finalize. loss = log(S_exp) - (dot(s_a,s_b)/N^2)*(1/T)
// ---------------------------------------------------------------------------
__global__ __launch_bounds__(256) void finalize_kernel(
    const float* __restrict__ s_a, const float* __restrict__ s_b,
    const float* __restrict__ S_exp, float* __restrict__ out) {
  const int tid = threadIdx.x;
  float p = 0.f;
  for (int d = tid; d < DD; d += 256) p += s_a[d] * s_b[d];
  #pragma unroll
  for (int off = 32; off > 0; off >>= 1) p += __shfl_down(p, off, 64);
  __shared__ float red[4];
  if ((tid & 63) == 0) red[tid >> 6] = p;
  __syncthreads();
  if (tid == 0) {
    const float dot = red[0] + red[1] + red[2] + red[3];
    out[0] = logf(S_exp[0]) - dot * (INV_T / ((float)NR * (float)NR));
  }
}

extern "C" void kernel_launch(void* const* d_in, const int* in_sizes, int n_in,
                              void* d_out, int out_size, void* d_ws, size_t ws_size,
                              hipStream_t stream) {
  const float* src = (const float*)d_in[0];
  const float* bc  = (const float*)d_in[1];
  const float* raw = (const float*)d_in[2];

  char* ws = (char*)d_ws;
  unsigned char* a8 = (unsigned char*)ws;                              // 8 MiB
  unsigned char* c8 = (unsigned char*)(ws + (size_t)8 * 1024 * 1024);  // 8 MiB
  float* inv_a = (float*)(ws + (size_t)16 * 1024 * 1024);              // 16 KiB
  float* inv_b = inv_a + NR;                                           // 16 KiB
  float* s_a   = inv_b + NR;                                           // 8 KiB
  float* s_b   = s_a + DD;                                             // 8 KiB
  float* S_exp = s_b + DD;                                             // 4 B

  // zero accumulators (ws is poisoned 0xAA before every launch)
  hipMemsetAsync(s_a, 0, (2 * DD + 1) * sizeof(float), stream);

  normalize_kernel<<<dim3(NR, 3), 256, 0, stream>>>(src, bc, raw, a8, c8, inv_a, inv_b);
  colsum_kernel<<<dim3(DD / 256, 32), 256, 0, stream>>>(src, bc, inv_a, inv_b, s_a, s_b);
  gemm_expsum_kernel<<<dim3(32, 32), 256, 0, stream>>>(a8, c8, S_exp);
  finalize_kernel<<<1, 256, 0, stream>>>(s_a, s_b, S_exp, (float*)d_out);
}